// Round 7
// baseline (322.553 us; speedup 1.0000x reference)
//
#include <hip/hip_runtime.h>
#include <hip/hip_bf16.h>
#include <stdint.h>

#ifndef DRNL
#define DRNL 64
#define HDIM 256
#endif

#define CHUNK 4096      // edges per hist/scatter block
#define BCAP 3072       // LDS edge capacity per bucket (avg 2046, 22 sigma)

typedef __attribute__((ext_vector_type(4))) float f32x4;      // MFMA C/D
typedef __attribute__((ext_vector_type(8))) _Float16 f16x8;   // 16B fp16 / MFMA A,B

// ---------------------------------------------------------------------------
// helpers
// ---------------------------------------------------------------------------
__device__ __forceinline__ void async16(void* lds, const void* g) {
    __builtin_amdgcn_global_load_lds(
        (const __attribute__((address_space(1))) void*)g,
        (__attribute__((address_space(3))) void*)(char*)lds, 16, 0, 0);
}

__device__ __forceinline__ int imin(int a, int b) { return a < b ? a : b; }

// ---------------------------------------------------------------------------
// k_misc (+merged k_hist): blocks [0,P) do the CSR edge histogram; blocks
// [P,..) do order-independent prep: W -> FRAGMENT-ORDER fp16, x16 convert
// (vectorized float4->f16x8), graph bounds.
// Fragment order: Wf[(((cg*KT + kt)*4 + ct)*64 + lane)*8 + j] =
//   W[k = kt*32 + (lane>>4)*8 + j][col = cg*64 + ct*16 + (lane&15)]
// ---------------------------------------------------------------------------
__global__ __launch_bounds__(256) void k_misc(
    const int* __restrict__ batch,
    const float* __restrict__ x,
    const float* __restrict__ W0, const float* __restrict__ W1,
    const float* __restrict__ W2,
    int* __restrict__ gstart,
    _Float16* __restrict__ x16,
    _Float16* __restrict__ W0t, _Float16* __restrict__ W1t,
    _Float16* __restrict__ W2t,
    const int* __restrict__ dst, int* __restrict__ ghist,
    int E, int P, int SH, int NBUCK,
    int N, int B) {
    const int tid = threadIdx.x;

    // ---- merged histogram part ----
    if (blockIdx.x < P) {
        __shared__ int h[512];
        int p = blockIdx.x;
        for (int i = tid; i < NBUCK; i += 256) h[i] = 0;
        __syncthreads();
        int e0 = p * CHUNK, e1 = imin(e0 + CHUNK, E);
        for (int e = e0 + tid; e < e1; e += 256)
            atomicAdd(&h[dst[e] >> SH], 1);          // LDS atomic
        __syncthreads();
        for (int b = tid; b < NBUCK; b += 256)
            ghist[(size_t)b * P + p] = h[b];
        return;
    }

    const int bid  = blockIdx.x - P;
    const int gsz  = (gridDim.x - P) * 256;
    const int gid0 = bid * 256 + tid;

    for (int i = gid0; i < (DRNL + 2 * HDIM) * 256; i += gsz) {
        int b = i >> 8, c = i & 255;
        const float* W; _Float16* T; int k, K;
        if (b < DRNL)            { W = W0; T = W0t; k = b;              K = DRNL; }
        else if (b < DRNL + 256) { W = W1; T = W1t; k = b - DRNL;       K = HDIM; }
        else                     { W = W2; T = W2t; k = b - DRNL - 256; K = HDIM; }
        int KT = K >> 5;
        int cg = c >> 6, ct = (c >> 4) & 3, cl = c & 15;
        int kt = k >> 5, qq = (k >> 3) & 3, j = k & 7;
        int lane = (qq << 4) | cl;
        T[(((size_t)(cg * KT + kt) * 4 + ct) * 64 + lane) * 8 + j] =
            (_Float16)W[(size_t)k * 256 + c];
    }

    // vectorized x -> fp16 (8 elems per thread-step)
    {
        const float4* x4 = (const float4*)x;
        f16x8* xv = (f16x8*)x16;
        int tot = N * DRNL / 8;
        for (int i = gid0; i < tot; i += gsz) {
            float4 a = x4[2 * i], b2 = x4[2 * i + 1];
            f16x8 o;
            o[0] = (_Float16)a.x;  o[1] = (_Float16)a.y;
            o[2] = (_Float16)a.z;  o[3] = (_Float16)a.w;
            o[4] = (_Float16)b2.x; o[5] = (_Float16)b2.y;
            o[6] = (_Float16)b2.z; o[7] = (_Float16)b2.w;
            xv[i] = o;
        }
    }

    for (int i = gid0; i <= N; i += gsz) {
        if (i == 0) {
            int b0 = batch[0];
            for (int b = 0; b <= b0; ++b) gstart[b] = 0;
        } else if (i == N) {
            int bl = batch[N - 1];
            for (int b = bl + 1; b <= B; ++b) gstart[b] = N;
        } else {
            int bp = batch[i - 1], bc = batch[i];
            if (bc != bp)
                for (int b = bp + 1; b <= bc; ++b) gstart[b] = i;
        }
    }
}

// ---------------------------------------------------------------------------
// CSR build, atomic-free. Bucket = dst >> SH (128 nodes/bucket).
// ---------------------------------------------------------------------------
__global__ __launch_bounds__(256) void k_gbase(int* __restrict__ ghist,
                                               int* __restrict__ btot, int P) {
    __shared__ int s[256];
    int b = blockIdx.x, tid = threadIdx.x;
    int* row = ghist + (size_t)b * P;
    int carry = 0;
    for (int base = 0; base < P; base += 256) {
        int idx = base + tid;
        int v = (idx < P) ? row[idx] : 0;
        s[tid] = v;
        __syncthreads();
        for (int o = 1; o < 256; o <<= 1) {
            int t = (tid >= o) ? s[tid - o] : 0;
            __syncthreads();
            s[tid] += t;
            __syncthreads();
        }
        if (idx < P) row[idx] = carry + s[tid] - v;
        carry += s[255];
        __syncthreads();
    }
    if (tid == 0) btot[b] = carry;
}

__global__ __launch_bounds__(256) void k_btscan(const int* __restrict__ btot,
                                                int* __restrict__ bbase,
                                                int* __restrict__ rowptr,
                                                int NBUCK, int N, int E) {
    __shared__ int s[256];
    int tid = threadIdx.x;
    int carry = 0;
    for (int base = 0; base < NBUCK; base += 256) {
        int idx = base + tid;
        int v = (idx < NBUCK) ? btot[idx] : 0;
        s[tid] = v;
        __syncthreads();
        for (int o = 1; o < 256; o <<= 1) {
            int t = (tid >= o) ? s[tid - o] : 0;
            __syncthreads();
            s[tid] += t;
            __syncthreads();
        }
        if (idx < NBUCK) bbase[idx] = carry + s[tid] - v;
        carry += s[255];
        __syncthreads();
    }
    if (tid == 0) { bbase[NBUCK] = E; rowptr[N] = E; }
}

__global__ __launch_bounds__(256) void k_scatter(const int* __restrict__ src,
                                                 const int* __restrict__ dst,
                                                 const int* __restrict__ ghist,
                                                 const int* __restrict__ bbase,
                                                 int* __restrict__ tmp,
                                                 int E, int P, int SH, int NBUCK) {
    __shared__ int base[512];
    int p = blockIdx.x, tid = threadIdx.x;
    for (int b = tid; b < NBUCK; b += 256)
        base[b] = bbase[b] + ghist[(size_t)b * P + p];
    __syncthreads();
    int e0 = p * CHUNK, e1 = imin(e0 + CHUNK, E);
    int msk = (1 << SH) - 1;
    for (int e = e0 + tid; e < e1; e += 256) {
        int d = dst[e];
        int r = atomicAdd(&base[d >> SH], 1);    // LDS atomic = cursor
        tmp[r] = (src[e] << SH) | (d & msk);
    }
}

__global__ __launch_bounds__(256) void k_bsort(const int* __restrict__ tmp,
                                               const int* __restrict__ bbase,
                                               int* __restrict__ col,
                                               int* __restrict__ rowptr,
                                               float* __restrict__ dis,
                                               _Float16* __restrict__ x16,
                                               int SH, int N) {
    __shared__ int cnt[512];
    __shared__ int off[512];
    __shared__ int sscan[256];
    __shared__ int eL[BCAP];
    __shared__ unsigned short rnk[BCAP];
    __shared__ int sL[BCAP];
    int b = blockIdx.x, tid = threadIdx.x;
    int nodes = 1 << SH, node0 = b << SH, msk = nodes - 1;
    int lo = bbase[b], hi = bbase[b + 1], m = hi - lo;
    bool fast = (m <= BCAP);

    for (int i = tid; i < nodes; i += 256) cnt[i] = 0;
    __syncthreads();
    if (fast) {
        for (int i = tid; i < m; i += 256) {
            int v = tmp[lo + i];
            eL[i] = v;
            rnk[i] = (unsigned short)atomicAdd(&cnt[v & msk], 1);
        }
    } else {
        for (int i = tid; i < m; i += 256)
            atomicAdd(&cnt[tmp[lo + i] & msk], 1);
    }
    __syncthreads();
    int carry = 0;
    for (int base = 0; base < nodes; base += 256) {
        int idx = base + tid;
        int v = (idx < nodes) ? cnt[idx] : 0;
        sscan[tid] = v;
        __syncthreads();
        for (int o = 1; o < 256; o <<= 1) {
            int t = (tid >= o) ? sscan[tid - o] : 0;
            __syncthreads();
            sscan[tid] += t;
            __syncthreads();
        }
        if (idx < nodes) off[idx] = carry + sscan[tid] - v;
        carry += sscan[255];
        __syncthreads();
    }
    for (int i = tid; i < nodes; i += 256) {
        int node = node0 + i;
        if (node < N) {
            rowptr[node] = lo + off[i];
            dis[node]    = rsqrtf((float)cnt[i] + 1.f);
        }
    }
    int rlim = imin(nodes, N - node0);
    for (int u = tid; u < rlim * 8; u += 256) {
        int r = u >> 3, c = u & 7;
        float d = rsqrtf((float)cnt[r] + 1.f);
        f16x8* xv = (f16x8*)(x16 + (size_t)(node0 + r) * 64);
        f16x8 v = xv[c];
        f16x8 o;
#pragma unroll
        for (int k = 0; k < 8; ++k) o[k] = (_Float16)((float)v[k] * d);
        xv[c] = o;
    }
    __syncthreads();   // cnt must stay intact until here
    if (fast) {
        for (int i = tid; i < m; i += 256) {
            int v = eL[i];
            sL[off[v & msk] + rnk[i]] = v >> SH;
        }
        __syncthreads();
        for (int i = tid; i < m; i += 256) col[lo + i] = sL[i];
    } else {
        for (int i = tid; i < nodes; i += 256) cnt[i] = 0;
        __syncthreads();
        for (int i = tid; i < m; i += 256) {
            int v = tmp[lo + i];
            int d = v & msk;
            int r = atomicAdd(&cnt[d], 1);
            col[lo + off[d] + r] = v >> SH;
        }
    }
}

// ---------------------------------------------------------------------------
// Aggregation over PRE-SCALED rows h' = h*dis, blocked-64 layout [FBLK][N][64].
// agg[dst] = dis[dst] * (sum_{src} h'[src] + h'[dst])  == exact GCN agg.
// WORK-STEALING version: 128 nodes/block, 32 octets pop nodes from an LDS
// cursor -> wave time ~ sum(deg)/8 instead of max(deg of 8) (removes ~1.4x
// Poisson max-of-8 skew of the static octet-per-node assignment).
// Per-node edge order unchanged -> bitwise-identical output.
// FBLK=4: feature block f pinned to XCD pair {2f,2f+1} via blockIdx%8.
// ---------------------------------------------------------------------------
template <int FBLK>
__global__ __launch_bounds__(256) void k_agg(const _Float16* __restrict__ hs,
                                             const float* __restrict__ dis,
                                             const int* __restrict__ rowptr,
                                             const int* __restrict__ col,
                                             _Float16* __restrict__ A16, int N) {
    __shared__ int cur;
    int node_wg, f;
    if constexpr (FBLK == 4) {
        int wg = blockIdx.x;
        int xcd = wg & 7;
        f = xcd >> 1;
        int half = xcd & 1;
        int NH = gridDim.x >> 3;
        node_wg = half * NH + (wg >> 3);
    } else {
        node_wg = blockIdx.x;
        f = 0;
    }
    if (threadIdx.x == 0) cur = 32;
    __syncthreads();
    const int base = node_wg * 128;
    const int lim  = imin(128, N - base);
    if (lim <= 0) return;
    const int lane  = threadIdx.x & 63;
    const int fl    = lane & 7;
    const int obase = lane & 56;           // octet base lane within wave
    const size_t boff = (size_t)f * ((size_t)N * 64);
    const f16x8* hv = (const f16x8*)(hs + boff);

    int myn = threadIdx.x >> 3;            // block-wide octet id = first node
    bool active = myn < lim;
    int gn = base + (active ? myn : 0);
    int j = 0, e1 = 0;
    if (active) { j = rowptr[gn]; e1 = rowptr[gn + 1]; }
    float acc[8];
#pragma unroll
    for (int k = 0; k < 8; ++k) acc[k] = 0.f;

    while (__any(active)) {
        if (active) {
            bool a0 = j < e1, a1 = j + 1 < e1, a2 = j + 2 < e1, a3 = j + 3 < e1;
            int s0 = col[a0 ? j : 0];
            int s1 = col[a1 ? j + 1 : 0];
            int s2 = col[a2 ? j + 2 : 0];
            int s3 = col[a3 ? j + 3 : 0];
            float m0 = a0 ? 1.f : 0.f, m1 = a1 ? 1.f : 0.f;
            float m2 = a2 ? 1.f : 0.f, m3 = a3 ? 1.f : 0.f;
            f16x8 v0 = hv[(size_t)s0 * 8 + fl];
            f16x8 v1 = hv[(size_t)s1 * 8 + fl];
            f16x8 v2 = hv[(size_t)s2 * 8 + fl];
            f16x8 v3 = hv[(size_t)s3 * 8 + fl];
#pragma unroll
            for (int k = 0; k < 8; ++k) acc[k] += m0 * (float)v0[k];
#pragma unroll
            for (int k = 0; k < 8; ++k) acc[k] += m1 * (float)v1[k];
#pragma unroll
            for (int k = 0; k < 8; ++k) acc[k] += m2 * (float)v2[k];
#pragma unroll
            for (int k = 0; k < 8; ++k) acc[k] += m3 * (float)v3[k];
            j += 4;
            if (j >= e1) {
                // finalize this node, then steal the next one
                float dn = dis[gn];
                f16x8 hsv = hv[(size_t)gn * 8 + fl];
                f16x8 o;
#pragma unroll
                for (int k = 0; k < 8; ++k)
                    o[k] = (_Float16)((acc[k] + (float)hsv[k]) * dn);
                __builtin_nontemporal_store(
                    o, (f16x8*)(A16 + boff + (size_t)gn * 64 + fl * 8));
#pragma unroll
                for (int k = 0; k < 8; ++k) acc[k] = 0.f;
                int nn = 0;
                if (fl == 0) nn = atomicAdd(&cur, 1);
                nn = __shfl(nn, obase);
                if (nn < lim) {
                    myn = nn; gn = base + myn;
                    j = rowptr[gn]; e1 = rowptr[gn + 1];
                } else {
                    active = false;
                }
            }
        }
    }
}

// ---------------------------------------------------------------------------
// MFMA GEMM, shared double-buffered staging: out = A@W + bias (+relu,+scale).
// A blocked [(K/64)][n][64] fp16; Wf fragment-ordered fp16; out [4][n][64].
// Fixes r6's 4x-redundant per-wave staging + per-strip vmcnt(0) drain:
//  - block = 4 waves (wave = 64-col group), 64 rows as 4 strips of 16.
//  - ONE shared strip stage per block (2 async16/thread, swizzled source),
//    double-buffered; next strip issued BEFORE compute (T3/T4).
//  - raw s_barrier + counted vmcnt(2) (leaves epilogue stores in flight;
//    guarantees stage(st+1) complete: newest 2 VMEM ops are the stores).
//  - buffer lifetime: buf[st&1] reads are lgkm-complete before the end-of-st
//    barrier; it is only rewritten at iter st+1 (stage st+2), after that
//    barrier -> no race.
//  - W panel: 32 coalesced f16x8 loads (fragment order), in VGPRs.
//  - epilogue: XOR-swizzled per-wave LDS transpose -> full-line f16x8 stores.
// ---------------------------------------------------------------------------
template <int K, int OUT_RELU, int SCALE>
__global__ __launch_bounds__(256, 2) void k_wgemm(const _Float16* __restrict__ A,
                                                  const _Float16* __restrict__ Wf,
                                                  const float* __restrict__ bias,
                                                  const float* __restrict__ dis,
                                                  _Float16* __restrict__ outh, int n) {
    constexpr int KT    = K / 32;           // 8 (K=256) or 2 (K=64)
    constexpr int CPR   = K / 8;            // 16B chunks per row
    constexpr int SLOTS = 16 * CPR;         // 16B slots per strip
    constexpr int SHW   = 16 * K;           // halfwords per strip buffer
    __shared__ _Float16 sA[2 * SHW];        // K=256: 16 KB; K=64: 4 KB
    __shared__ _Float16 sOut[4 * 16 * 64];  // 8 KB per-wave transpose buffers

    const int tid  = threadIdx.x;
    const int lane = tid & 63;
    const int wv   = tid >> 6;              // wave = 64-col group
    const int c15  = lane & 15;
    const int q    = lane >> 4;
    const int row0 = blockIdx.x * 64;
    const size_t bstride = (size_t)n * 64;
    _Float16* sO = sOut + wv * (16 * 64);
    _Float16* ob = outh + (size_t)wv * bstride;   // out feature block = wv

    // cooperative stage of strip st into buffer b (linear LDS dest,
    // inverse-swizzled global source: LDS chunk chs holds global chunk
    // chs ^ (row&7))
    auto stage = [&](int b, int st) {
        const int r0 = row0 + (st << 4);
        _Float16* dstp = sA + b * SHW;
#pragma unroll
        for (int i = 0; i < (SLOTS + 255) / 256; ++i) {
            int s = (i << 8) + tid;
            if (SLOTS % 256 == 0 || s < SLOTS) {   // wave-uniform mask
                int row = s / CPR;
                int chs = s % CPR;
                int cg  = chs ^ (row & 7);
                int gr  = imin(r0 + row, n - 1);
                async16(dstp + (size_t)s * 8,
                        A + (size_t)(cg >> 3) * bstride + (size_t)gr * 64 +
                            (cg & 7) * 8);
            }
        }
    };

    stage(0, 0);   // issue first strip before W loads (overlap HBM latency)

    // ---- W panel: fully-coalesced 16B loads, fragment order ----
    f16x8 wf[4][KT];
    const _Float16* wp = Wf + ((size_t)wv * KT * 4 * 64 + lane) * 8;
#pragma unroll
    for (int kt = 0; kt < KT; ++kt)
#pragma unroll
        for (int ct = 0; ct < 4; ++ct)
            wf[ct][kt] = *(const f16x8*)(wp + (size_t)((kt * 4 + ct) * 64) * 8);

    // ---- bias / dis via coalesced load + shfl ----
    float bvl = bias[(wv << 6) + lane];
    float bv[4];
#pragma unroll
    for (int ct = 0; ct < 4; ++ct) bv[ct] = __shfl(bvl, (ct << 4) + c15);

    float dsv[4][4];
    if (SCALE) {
        float dvl = dis[imin(row0 + lane, n - 1)];
#pragma unroll
        for (int st = 0; st < 4; ++st)
#pragma unroll
            for (int r = 0; r < 4; ++r)
                dsv[st][r] = __shfl(dvl, (st << 4) + (q << 2) + r);
    }

    asm volatile("s_waitcnt vmcnt(0)" ::: "memory");
    __builtin_amdgcn_sched_barrier(0);
    __builtin_amdgcn_s_barrier();

#pragma unroll
    for (int st = 0; st < 4; ++st) {
        if (st < 3) stage((st + 1) & 1, st + 1);   // prefetch next strip

        const _Float16* buf = sA + (st & 1) * SHW;
        f16x8 af[KT];
#pragma unroll
        for (int kt = 0; kt < KT; ++kt) {
            int cg = kt * 4 + q;
            af[kt] = *(const f16x8*)(buf + c15 * K + ((cg ^ (c15 & 7)) * 8));
        }

        f32x4 acc[4];
#pragma unroll
        for (int ct = 0; ct < 4; ++ct) acc[ct] = (f32x4)0.f;
#pragma unroll
        for (int kt = 0; kt < KT; ++kt)
#pragma unroll
            for (int ct = 0; ct < 4; ++ct)
                acc[ct] = __builtin_amdgcn_mfma_f32_16x16x32_f16(
                    af[kt], wf[ct][kt], acc[ct], 0, 0, 0);

        // ---- epilogue: swizzled per-wave LDS transpose -> coalesced store
        const int r0 = row0 + (st << 4);
#pragma unroll
        for (int ct = 0; ct < 4; ++ct) {
#pragma unroll
            for (int r = 0; r < 4; ++r) {
                float v = acc[ct][r] + bv[ct];
                if (OUT_RELU) v = fmaxf(v, 0.f);
                if (SCALE) v *= dsv[st][r];
                int row = (q << 2) + r;
                int colx = (ct << 4) + c15;
                int sw = (((colx >> 3) ^ (row & 7)) << 3) | (colx & 7);
                sO[row * 64 + sw] = (_Float16)v;
            }
        }
#pragma unroll
        for (int ps = 0; ps < 2; ++ps) {
            int u = (ps << 6) + lane;       // 0..127
            int rr = u >> 3, ch2 = u & 7;
            f16x8 vv = *(const f16x8*)(sO + rr * 64 + ((ch2 ^ (rr & 7)) << 3));
            if (r0 + rr < n)
                *(f16x8*)(ob + (size_t)(r0 + rr) * 64 + ch2 * 8) = vv;
        }

        if (st < 3) {
            // stage(st+1) done when <=2 newest (this strip's 2 stores) remain
            asm volatile("s_waitcnt vmcnt(2)" ::: "memory");
            __builtin_amdgcn_sched_barrier(0);
            __builtin_amdgcn_s_barrier();
        }
    }
}

// ---------------------------------------------------------------------------
// fused head: mean-pool + concat + MLP -> out[b]. one block per graph.
// h blocked [4][N][64].
// ---------------------------------------------------------------------------
__global__ __launch_bounds__(256) void k_head(const _Float16* __restrict__ h,
                                              const int* __restrict__ gstart,
                                              const int* __restrict__ u,
                                              const int* __restrict__ v,
                                              const float* __restrict__ Wm1,
                                              const float* __restrict__ bm1,
                                              const float* __restrict__ Wm2,
                                              const float* __restrict__ bm2,
                                              float* __restrict__ out, int N) {
    int b = blockIdx.x;
    int t = threadIdx.x;
    __shared__ float z[3 * HDIM];
    __shared__ float red[4];
    const _Float16* hb = h + (size_t)(t >> 6) * ((size_t)N * 64) + (t & 63);
    int s = gstart[b], e = gstart[b + 1];
    float pa = 0.f;
    int i = s;
    for (; i + 3 < e; i += 4) {
        float a0 = (float)hb[(size_t)i * 64];
        float a1 = (float)hb[(size_t)(i + 1) * 64];
        float a2 = (float)hb[(size_t)(i + 2) * 64];
        float a3 = (float)hb[(size_t)(i + 3) * 64];
        pa += (a0 + a1) + (a2 + a3);
    }
    for (; i < e; ++i) pa += (float)hb[(size_t)i * 64];
    z[t]            = pa / fmaxf((float)(e - s), 1.f);
    z[HDIM + t]     = (float)hb[(size_t)u[b] * 64];
    z[2 * HDIM + t] = (float)hb[(size_t)v[b] * 64];
    __syncthreads();
    float acc[8];
#pragma unroll
    for (int k = 0; k < 8; ++k) acc[k] = 0.f;
    for (int k = 0; k < 3 * HDIM; k += 8) {
#pragma unroll
        for (int jj = 0; jj < 8; ++jj)
            acc[jj] = fmaf(z[k + jj], Wm1[(size_t)(k + jj) * HDIM + t], acc[jj]);
    }
    float sum = (((acc[0] + acc[1]) + (acc[2] + acc[3])) +
                 ((acc[4] + acc[5]) + (acc[6] + acc[7]))) + bm1[t];
    float hid = fmaxf(sum, 0.f);
    float p = hid * Wm2[t];
    for (int off = 32; off; off >>= 1) p += __shfl_down(p, off);
    if ((t & 63) == 0) red[t >> 6] = p;
    __syncthreads();
    if (t == 0) out[b] = red[0] + red[1] + red[2] + red[3] + bm2[0];
}

// ---------------------------------------------------------------------------
extern "C" void kernel_launch(void* const* d_in, const int* in_sizes, int n_in,
                              void* d_out, int out_size, void* d_ws, size_t ws_size,
                              hipStream_t stream) {
    const float* x    = (const float*)d_in[0];
    const int*   ei   = (const int*)d_in[1];
    const int*   batc = (const int*)d_in[2];
    const int*   uidx = (const int*)d_in[3];
    const int*   vidx = (const int*)d_in[4];
    const float* W0   = (const float*)d_in[5];
    const float* b0   = (const float*)d_in[6];
    const float* W1   = (const float*)d_in[7];
    const float* b1   = (const float*)d_in[8];
    const float* W2   = (const float*)d_in[9];
    const float* b2   = (const float*)d_in[10];
    const float* Wm1  = (const float*)d_in[11];
    const float* bm1  = (const float*)d_in[12];
    const float* Wm2  = (const float*)d_in[13];
    const float* bm2  = (const float*)d_in[14];
    float* out = (float*)d_out;

    const int N = in_sizes[0] / DRNL;
    const int E = in_sizes[1] / 2;
    const int B = in_sizes[3];
    const int* src = ei;
    const int* dst = ei + E;

    int SH = 7;
    while (((N + (1 << SH) - 1) >> SH) > 512) ++SH;
    const int NBUCK = (N + (1 << SH) - 1) >> SH;
    const int P = (E + CHUNK - 1) / CHUNK;

    char* w = (char*)d_ws;
    size_t off = 0;
    auto carve = [&](size_t bytes) {
        void* p = w + off;
        off = (off + bytes + 255) & ~(size_t)255;
        return p;
    };
    int*       rowptr = (int*)carve((size_t)(N + 1) * 4);
    int*       colA   = (int*)carve((size_t)E * 4);
    float*     dis    = (float*)carve((size_t)N * 4);
    int*       gstart = (int*)carve((size_t)(B + 1) * 4);
    _Float16*  A16    = (_Float16*)carve((size_t)N * HDIM * 2);
    _Float16*  h16    = (_Float16*)carve((size_t)N * HDIM * 2);
    _Float16*  x16    = (_Float16*)carve((size_t)N * DRNL * 2);
    _Float16*  W0t    = (_Float16*)carve((size_t)DRNL * HDIM * 2);
    _Float16*  W1t    = (_Float16*)carve((size_t)HDIM * HDIM * 2);
    _Float16*  W2t    = (_Float16*)carve((size_t)HDIM * HDIM * 2);
    int*       ghist  = (int*)carve((size_t)NBUCK * P * 4);
    int*       btot   = (int*)carve(512 * 4);
    int*       bbase  = (int*)carve(513 * 4);
    int*       tmpE   = (int*)carve((size_t)E * 4);
    (void)ws_size;

    // prep + histogram in one launch (hist blocks [0,P), misc blocks [P,..))
    k_misc<<<P + 1024, 256, 0, stream>>>(batc, x, W0, W1, W2, gstart,
                                         x16, W0t, W1t, W2t,
                                         dst, ghist, E, P, SH, NBUCK, N, B);
    // atomic-free CSR build (also emits rowptr, dis, and prescales x16)
    k_gbase<<<NBUCK, 256, 0, stream>>>(ghist, btot, P);
    k_btscan<<<1, 256, 0, stream>>>(btot, bbase, rowptr, NBUCK, N, E);
    k_scatter<<<P, 256, 0, stream>>>(src, dst, ghist, bbase, tmpE, E, P, SH, NBUCK);
    k_bsort<<<NBUCK, 256, 0, stream>>>(tmpE, bbase, colA, rowptr, dis, x16, SH, N);

    int gemmb = (N + 63) / 64;      // one 64-row block per k_wgemm block
    int NB128 = (N + 127) / 128;    // agg node-WGs (128 nodes each)
    int NH = (NB128 + 1) / 2;       // node-WGs per XCD-pair half
    int aggb4 = 8 * NH;             // FBLK=4 grid (multiple of 8)

    // layer 0: agg(x') -> GEMM (relu, scale) -> h' blocked-64
    k_agg<1><<<NB128, 256, 0, stream>>>(x16, dis, rowptr, colA, A16, N);
    k_wgemm<DRNL, 1, 1><<<gemmb, 256, 0, stream>>>(A16, W0t, b0, dis, h16, N);
    // layer 1: agg(h') -> GEMM (relu, scale) -> h'
    k_agg<4><<<aggb4, 256, 0, stream>>>(h16, dis, rowptr, colA, A16, N);
    k_wgemm<HDIM, 1, 1><<<gemmb, 256, 0, stream>>>(A16, W1t, b1, dis, h16, N);
    // layer 2: agg(h') -> GEMM (no relu, RAW output for head)
    k_agg<4><<<aggb4, 256, 0, stream>>>(h16, dis, rowptr, colA, A16, N);
    k_wgemm<HDIM, 0, 0><<<gemmb, 256, 0, stream>>>(A16, W2t, b2, dis, h16, N);

    // fused mean-pool + MLP head
    k_head<<<B, 256, 0, stream>>>(h16, gstart, uidx, vidx, Wm1, bm1, Wm2, bm2, out, N);
}

// Round 8
// 304.877 us; speedup vs baseline: 1.0580x; 1.0580x over previous
//
#include <hip/hip_runtime.h>
#include <hip/hip_bf16.h>
#include <stdint.h>

#ifndef DRNL
#define DRNL 64
#define HDIM 256
#endif

#define CHUNK 4096      // edges per hist/scatter block
#define BCAP 3072       // LDS edge capacity per bucket (avg 2046, 22 sigma)

typedef __attribute__((ext_vector_type(4))) float f32x4;      // MFMA C/D
typedef __attribute__((ext_vector_type(8))) _Float16 f16x8;   // 16B fp16 / MFMA A,B

// ---------------------------------------------------------------------------
// helpers
// ---------------------------------------------------------------------------
__device__ __forceinline__ void async16(void* lds, const void* g) {
    __builtin_amdgcn_global_load_lds(
        (const __attribute__((address_space(1))) void*)g,
        (__attribute__((address_space(3))) void*)(char*)lds, 16, 0, 0);
}

__device__ __forceinline__ int imin(int a, int b) { return a < b ? a : b; }

// ---------------------------------------------------------------------------
// k_misc (+merged hist): blocks [0,P) do the CSR edge histogram; blocks
// [P,..) do order-independent prep: W -> FRAGMENT-ORDER fp16, x16 convert
// (vectorized float4->f16x8), graph bounds.
// Fragment order: Wf[(((cg*KT + kt)*4 + ct)*64 + lane)*8 + j] =
//   W[k = kt*32 + (lane>>4)*8 + j][col = cg*64 + ct*16 + (lane&15)]
// ---------------------------------------------------------------------------
__global__ __launch_bounds__(256) void k_misc(
    const int* __restrict__ batch,
    const float* __restrict__ x,
    const float* __restrict__ W0, const float* __restrict__ W1,
    const float* __restrict__ W2,
    int* __restrict__ gstart,
    _Float16* __restrict__ x16,
    _Float16* __restrict__ W0t, _Float16* __restrict__ W1t,
    _Float16* __restrict__ W2t,
    const int* __restrict__ dst, int* __restrict__ ghist,
    int E, int P, int SH, int NBUCK,
    int N, int B) {
    const int tid = threadIdx.x;

    // ---- merged histogram part ----
    if (blockIdx.x < P) {
        __shared__ int h[512];
        int p = blockIdx.x;
        for (int i = tid; i < NBUCK; i += 256) h[i] = 0;
        __syncthreads();
        int e0 = p * CHUNK, e1 = imin(e0 + CHUNK, E);
        for (int e = e0 + tid; e < e1; e += 256)
            atomicAdd(&h[dst[e] >> SH], 1);          // LDS atomic
        __syncthreads();
        for (int b = tid; b < NBUCK; b += 256)
            ghist[(size_t)b * P + p] = h[b];
        return;
    }

    const int bid  = blockIdx.x - P;
    const int gsz  = (gridDim.x - P) * 256;
    const int gid0 = bid * 256 + tid;

    for (int i = gid0; i < (DRNL + 2 * HDIM) * 256; i += gsz) {
        int b = i >> 8, c = i & 255;
        const float* W; _Float16* T; int k, K;
        if (b < DRNL)            { W = W0; T = W0t; k = b;              K = DRNL; }
        else if (b < DRNL + 256) { W = W1; T = W1t; k = b - DRNL;       K = HDIM; }
        else                     { W = W2; T = W2t; k = b - DRNL - 256; K = HDIM; }
        int KT = K >> 5;
        int cg = c >> 6, ct = (c >> 4) & 3, cl = c & 15;
        int kt = k >> 5, qq = (k >> 3) & 3, j = k & 7;
        int lane = (qq << 4) | cl;
        T[(((size_t)(cg * KT + kt) * 4 + ct) * 64 + lane) * 8 + j] =
            (_Float16)W[(size_t)k * 256 + c];
    }

    // vectorized x -> fp16 (8 elems per thread-step)
    {
        const float4* x4 = (const float4*)x;
        f16x8* xv = (f16x8*)x16;
        int tot = N * DRNL / 8;
        for (int i = gid0; i < tot; i += gsz) {
            float4 a = x4[2 * i], b2 = x4[2 * i + 1];
            f16x8 o;
            o[0] = (_Float16)a.x;  o[1] = (_Float16)a.y;
            o[2] = (_Float16)a.z;  o[3] = (_Float16)a.w;
            o[4] = (_Float16)b2.x; o[5] = (_Float16)b2.y;
            o[6] = (_Float16)b2.z; o[7] = (_Float16)b2.w;
            xv[i] = o;
        }
    }

    for (int i = gid0; i <= N; i += gsz) {
        if (i == 0) {
            int b0 = batch[0];
            for (int b = 0; b <= b0; ++b) gstart[b] = 0;
        } else if (i == N) {
            int bl = batch[N - 1];
            for (int b = bl + 1; b <= B; ++b) gstart[b] = N;
        } else {
            int bp = batch[i - 1], bc = batch[i];
            if (bc != bp)
                for (int b = bp + 1; b <= bc; ++b) gstart[b] = i;
        }
    }
}

// ---------------------------------------------------------------------------
// CSR build, atomic-free. Bucket = dst >> SH (128 nodes/bucket).
// ---------------------------------------------------------------------------
__global__ __launch_bounds__(256) void k_gbase(int* __restrict__ ghist,
                                               int* __restrict__ btot, int P) {
    __shared__ int s[256];
    int b = blockIdx.x, tid = threadIdx.x;
    int* row = ghist + (size_t)b * P;
    int carry = 0;
    for (int base = 0; base < P; base += 256) {
        int idx = base + tid;
        int v = (idx < P) ? row[idx] : 0;
        s[tid] = v;
        __syncthreads();
        for (int o = 1; o < 256; o <<= 1) {
            int t = (tid >= o) ? s[tid - o] : 0;
            __syncthreads();
            s[tid] += t;
            __syncthreads();
        }
        if (idx < P) row[idx] = carry + s[tid] - v;
        carry += s[255];
        __syncthreads();
    }
    if (tid == 0) btot[b] = carry;
}

__global__ __launch_bounds__(256) void k_btscan(const int* __restrict__ btot,
                                                int* __restrict__ bbase,
                                                int* __restrict__ rowptr,
                                                int NBUCK, int N, int E) {
    __shared__ int s[256];
    int tid = threadIdx.x;
    int carry = 0;
    for (int base = 0; base < NBUCK; base += 256) {
        int idx = base + tid;
        int v = (idx < NBUCK) ? btot[idx] : 0;
        s[tid] = v;
        __syncthreads();
        for (int o = 1; o < 256; o <<= 1) {
            int t = (tid >= o) ? s[tid - o] : 0;
            __syncthreads();
            s[tid] += t;
            __syncthreads();
        }
        if (idx < NBUCK) bbase[idx] = carry + s[tid] - v;
        carry += s[255];
        __syncthreads();
    }
    if (tid == 0) { bbase[NBUCK] = E; rowptr[N] = E; }
}

__global__ __launch_bounds__(256) void k_scatter(const int* __restrict__ src,
                                                 const int* __restrict__ dst,
                                                 const int* __restrict__ ghist,
                                                 const int* __restrict__ bbase,
                                                 int* __restrict__ tmp,
                                                 int E, int P, int SH, int NBUCK) {
    __shared__ int base[512];
    int p = blockIdx.x, tid = threadIdx.x;
    for (int b = tid; b < NBUCK; b += 256)
        base[b] = bbase[b] + ghist[(size_t)b * P + p];
    __syncthreads();
    int e0 = p * CHUNK, e1 = imin(e0 + CHUNK, E);
    int msk = (1 << SH) - 1;
    for (int e = e0 + tid; e < e1; e += 256) {
        int d = dst[e];
        int r = atomicAdd(&base[d >> SH], 1);    // LDS atomic = cursor
        tmp[r] = (src[e] << SH) | (d & msk);
    }
}

__global__ __launch_bounds__(256) void k_bsort(const int* __restrict__ tmp,
                                               const int* __restrict__ bbase,
                                               int* __restrict__ col,
                                               int* __restrict__ rowptr,
                                               float* __restrict__ dis,
                                               _Float16* __restrict__ x16,
                                               int SH, int N) {
    __shared__ int cnt[512];
    __shared__ int off[512];
    __shared__ int sscan[256];
    __shared__ int eL[BCAP];
    __shared__ unsigned short rnk[BCAP];
    __shared__ int sL[BCAP];
    int b = blockIdx.x, tid = threadIdx.x;
    int nodes = 1 << SH, node0 = b << SH, msk = nodes - 1;
    int lo = bbase[b], hi = bbase[b + 1], m = hi - lo;
    bool fast = (m <= BCAP);

    for (int i = tid; i < nodes; i += 256) cnt[i] = 0;
    __syncthreads();
    if (fast) {
        for (int i = tid; i < m; i += 256) {
            int v = tmp[lo + i];
            eL[i] = v;
            rnk[i] = (unsigned short)atomicAdd(&cnt[v & msk], 1);
        }
    } else {
        for (int i = tid; i < m; i += 256)
            atomicAdd(&cnt[tmp[lo + i] & msk], 1);
    }
    __syncthreads();
    int carry = 0;
    for (int base = 0; base < nodes; base += 256) {
        int idx = base + tid;
        int v = (idx < nodes) ? cnt[idx] : 0;
        sscan[tid] = v;
        __syncthreads();
        for (int o = 1; o < 256; o <<= 1) {
            int t = (tid >= o) ? sscan[tid - o] : 0;
            __syncthreads();
            sscan[tid] += t;
            __syncthreads();
        }
        if (idx < nodes) off[idx] = carry + sscan[tid] - v;
        carry += sscan[255];
        __syncthreads();
    }
    for (int i = tid; i < nodes; i += 256) {
        int node = node0 + i;
        if (node < N) {
            rowptr[node] = lo + off[i];
            dis[node]    = rsqrtf((float)cnt[i] + 1.f);
        }
    }
    int rlim = imin(nodes, N - node0);
    for (int u = tid; u < rlim * 8; u += 256) {
        int r = u >> 3, c = u & 7;
        float d = rsqrtf((float)cnt[r] + 1.f);
        f16x8* xv = (f16x8*)(x16 + (size_t)(node0 + r) * 64);
        f16x8 v = xv[c];
        f16x8 o;
#pragma unroll
        for (int k = 0; k < 8; ++k) o[k] = (_Float16)((float)v[k] * d);
        xv[c] = o;
    }
    __syncthreads();   // cnt must stay intact until here
    if (fast) {
        for (int i = tid; i < m; i += 256) {
            int v = eL[i];
            sL[off[v & msk] + rnk[i]] = v >> SH;
        }
        __syncthreads();
        for (int i = tid; i < m; i += 256) col[lo + i] = sL[i];
    } else {
        for (int i = tid; i < nodes; i += 256) cnt[i] = 0;
        __syncthreads();
        for (int i = tid; i < m; i += 256) {
            int v = tmp[lo + i];
            int d = v & msk;
            int r = atomicAdd(&cnt[d], 1);
            col[lo + off[d] + r] = v >> SH;
        }
    }
}

// ---------------------------------------------------------------------------
// Aggregation over PRE-SCALED rows h' = h*dis, blocked-64 layout [FBLK][N][64].
// agg[dst] = dis[dst] * (sum_{src} h'[src] + h'[dst])  == exact GCN agg.
// STATIC octet-per-node (r7's work-stealing regressed: steal path every ~4
// iters serialized the loop). 8-lane octet owns one node, walks its edge
// list with EIGHT independent gathers in flight per iteration (was 4):
// halves latency-exposed loop trips (deg 16 -> 2 trips).
// FBLK=4: feature block f pinned to XCD pair {2f,2f+1} via blockIdx%8.
// Per-node edge order unchanged -> bitwise-identical output.
// ---------------------------------------------------------------------------
template <int FBLK>
__global__ __launch_bounds__(256) void k_agg(const _Float16* __restrict__ hs,
                                             const float* __restrict__ dis,
                                             const int* __restrict__ rowptr,
                                             const int* __restrict__ col,
                                             _Float16* __restrict__ A16, int N) {
    int node_wg, f;
    if constexpr (FBLK == 4) {
        int wg = blockIdx.x;
        int xcd = wg & 7;
        f = xcd >> 1;
        int half = xcd & 1;
        int NH = gridDim.x >> 3;
        node_wg = half * NH + (wg >> 3);
    } else {
        node_wg = blockIdx.x;
        f = 0;
    }
    int lane = threadIdx.x & 63;
    int wv = threadIdx.x >> 6;
    int oct = lane >> 3;
    int fl = lane & 7;
    int gw = node_wg * 32 + wv * 8 + oct;
    bool valid = gw < N;
    int gwc = valid ? gw : N - 1;
    const size_t boff = (size_t)f * ((size_t)N * 64);
    const f16x8* hv = (const f16x8*)(hs + boff);
    float acc[8];
#pragma unroll
    for (int k = 0; k < 8; ++k) acc[k] = 0.f;

    int e0 = rowptr[gwc];
    int e1 = valid ? rowptr[gwc + 1] : e0;
    int j = e0;
    while (__any(j < e1)) {
        int   idx[8];
        float mm[8];
        f16x8 vv[8];
#pragma unroll
        for (int u = 0; u < 8; ++u) {
            bool a = (j + u) < e1;
            idx[u] = col[a ? j + u : 0];
            mm[u]  = a ? 1.f : 0.f;
        }
#pragma unroll
        for (int u = 0; u < 8; ++u)
            vv[u] = hv[(size_t)idx[u] * 8 + fl];
#pragma unroll
        for (int u = 0; u < 8; ++u)
#pragma unroll
            for (int k = 0; k < 8; ++k)
                acc[k] += mm[u] * (float)vv[u][k];
        j += 8;
    }

    float dn = dis[gwc];
    f16x8 hsv = hv[(size_t)gwc * 8 + fl];
    f16x8 o;
#pragma unroll
    for (int k = 0; k < 8; ++k)
        o[k] = (_Float16)((acc[k] + (float)hsv[k]) * dn);
    if (valid)
        __builtin_nontemporal_store(
            o, (f16x8*)(A16 + boff + (size_t)gw * 64 + fl * 8));
}

// ---------------------------------------------------------------------------
// Barrier-free, fully-coalesced register-W GEMM (r6-proven): out = A@W + bias
// (+relu, +dis scale). A blocked [(K/64)][n][64] fp16; Wf fragment-ordered;
// out blocked [4][n][64].
//  - wave wv owns 64-col group, 64 rows as 4 strips of 16; NO __syncthreads.
//  - W panel: 32 coalesced f16x8 loads (fragment-order), held in VGPRs.
//  - A strip: per-WAVE global_load_lds (coalesced, linear LDS dest,
//    inverse-XOR-swizzled global source) -> wave-local vmcnt(0) ->
//    conflict-free swizzled ds_read_b128 frags.
//  - bias/dis: one coalesced load + __shfl.
//  - epilogue: XOR-swizzled per-wave LDS transpose -> full-line f16x8 stores.
// ---------------------------------------------------------------------------
template <int K, int OUT_RELU, int SCALE>
__global__ __launch_bounds__(256, 1) void k_wgemm(const _Float16* __restrict__ A,
                                                  const _Float16* __restrict__ Wf,
                                                  const float* __restrict__ bias,
                                                  const float* __restrict__ dis,
                                                  _Float16* __restrict__ outh, int n) {
    constexpr int KT  = K / 32;             // k-tiles: 8 (K=256) or 2 (K=64)
    constexpr int NFB = K / 64;             // feature blocks in A
    constexpr int NI  = NFB * 2;            // async16 instrs per strip
    constexpr int STG = NFB * 1024;         // stage halfwords per wave (2KB/fb)
    __shared__ _Float16 sAll[4 * (STG + 1024)];   // per wave: stage + 2KB sO

    const int tid  = threadIdx.x;
    const int lane = tid & 63;
    const int wv   = tid >> 6;              // wave = 64-col group
    const int c15  = lane & 15;
    const int q    = lane >> 4;
    const int row0 = blockIdx.x * 64;
    const size_t bstride = (size_t)n * 64;
    _Float16* sbuf = sAll + wv * (STG + 1024);
    _Float16* sO   = sbuf + STG;
    _Float16* ob   = outh + (size_t)wv * bstride;   // out feature block = wv

    // ---- W panel: 32 (or 8) fully-coalesced 16B loads, fragment order ----
    f16x8 wf[4][KT];
    const _Float16* wp = Wf + ((size_t)wv * KT * 4 * 64 + lane) * 8;
#pragma unroll
    for (int kt = 0; kt < KT; ++kt)
#pragma unroll
        for (int ct = 0; ct < 4; ++ct)
            wf[ct][kt] = *(const f16x8*)(wp + (size_t)((kt * 4 + ct) * 64) * 8);

    // ---- bias / dis via coalesced load + shfl ----
    float bvl = bias[(wv << 6) + lane];
    float bv[4];
#pragma unroll
    for (int ct = 0; ct < 4; ++ct) bv[ct] = __shfl(bvl, (ct << 4) + c15);

    float dsv[4][4];
    if (SCALE) {
        float dvl = dis[imin(row0 + lane, n - 1)];
#pragma unroll
        for (int st = 0; st < 4; ++st)
#pragma unroll
            for (int r = 0; r < 4; ++r)
                dsv[st][r] = __shfl(dvl, (st << 4) + (q << 2) + r);
    }

#pragma unroll
    for (int st = 0; st < 4; ++st) {
        const int r0 = row0 + (st << 4);
        // ---- stage strip (16 rows x K feats) into per-wave LDS ----
        // linear LDS dest; global source pre-swizzled so that swizzled
        // ds_read below sees chunk ch of row at cs = ch ^ (row&7).
#pragma unroll
        for (int i = 0; i < NI; ++i) {
            int s   = (i << 6) + lane;      // 16B slot
            int fb  = s >> 7;
            int row = (s >> 3) & 15;
            int ch  = (s & 7) ^ (row & 7);
            int gr  = imin(r0 + row, n - 1);
            async16(sbuf + (size_t)s * 8,
                    A + (size_t)fb * bstride + (size_t)gr * 64 + ch * 8);
        }
        asm volatile("s_waitcnt vmcnt(0)" ::: "memory");   // wave-local wait
        __builtin_amdgcn_sched_barrier(0);

        // ---- frags: conflict-free swizzled ds_read_b128 ----
        f16x8 af[KT];
#pragma unroll
        for (int kt = 0; kt < KT; ++kt) {
            int off = (kt >> 1) * 1024 + c15 * 64 +
                      ((((kt & 1) * 4 + q) ^ (c15 & 7)) * 8);
            af[kt] = *(const f16x8*)(sbuf + off);
        }

        f32x4 acc[4];
#pragma unroll
        for (int ct = 0; ct < 4; ++ct) acc[ct] = (f32x4)0.f;
#pragma unroll
        for (int kt = 0; kt < KT; ++kt)
#pragma unroll
            for (int ct = 0; ct < 4; ++ct)
                acc[ct] = __builtin_amdgcn_mfma_f32_16x16x32_f16(
                    af[kt], wf[ct][kt], acc[ct], 0, 0, 0);

        // ---- epilogue: swizzled per-wave LDS transpose -> coalesced store
#pragma unroll
        for (int ct = 0; ct < 4; ++ct) {
#pragma unroll
            for (int r = 0; r < 4; ++r) {
                float v = acc[ct][r] + bv[ct];
                if (OUT_RELU) v = fmaxf(v, 0.f);
                if (SCALE) v *= dsv[st][r];
                int row = (q << 2) + r;
                int colx = (ct << 4) + c15;
                int sw = (((colx >> 3) ^ (row & 7)) << 3) | (colx & 7);
                sO[row * 64 + sw] = (_Float16)v;
            }
        }
#pragma unroll
        for (int ps = 0; ps < 2; ++ps) {
            int u = (ps << 6) + lane;       // 0..127
            int rr = u >> 3, ch2 = u & 7;
            f16x8 vv = *(const f16x8*)(sO + rr * 64 + ((ch2 ^ (rr & 7)) << 3));
            if (r0 + rr < n)
                *(f16x8*)(ob + (size_t)(r0 + rr) * 64 + ch2 * 8) = vv;
        }
    }
}

// ---------------------------------------------------------------------------
// fused head: mean-pool + concat + MLP -> out[b]. one block per graph.
// h blocked [4][N][64].
// ---------------------------------------------------------------------------
__global__ __launch_bounds__(256) void k_head(const _Float16* __restrict__ h,
                                              const int* __restrict__ gstart,
                                              const int* __restrict__ u,
                                              const int* __restrict__ v,
                                              const float* __restrict__ Wm1,
                                              const float* __restrict__ bm1,
                                              const float* __restrict__ Wm2,
                                              const float* __restrict__ bm2,
                                              float* __restrict__ out, int N) {
    int b = blockIdx.x;
    int t = threadIdx.x;
    __shared__ float z[3 * HDIM];
    __shared__ float red[4];
    const _Float16* hb = h + (size_t)(t >> 6) * ((size_t)N * 64) + (t & 63);
    int s = gstart[b], e = gstart[b + 1];
    float pa = 0.f;
    int i = s;
    for (; i + 3 < e; i += 4) {
        float a0 = (float)hb[(size_t)i * 64];
        float a1 = (float)hb[(size_t)(i + 1) * 64];
        float a2 = (float)hb[(size_t)(i + 2) * 64];
        float a3 = (float)hb[(size_t)(i + 3) * 64];
        pa += (a0 + a1) + (a2 + a3);
    }
    for (; i < e; ++i) pa += (float)hb[(size_t)i * 64];
    z[t]            = pa / fmaxf((float)(e - s), 1.f);
    z[HDIM + t]     = (float)hb[(size_t)u[b] * 64];
    z[2 * HDIM + t] = (float)hb[(size_t)v[b] * 64];
    __syncthreads();
    float acc[8];
#pragma unroll
    for (int k = 0; k < 8; ++k) acc[k] = 0.f;
    for (int k = 0; k < 3 * HDIM; k += 8) {
#pragma unroll
        for (int jj = 0; jj < 8; ++jj)
            acc[jj] = fmaf(z[k + jj], Wm1[(size_t)(k + jj) * HDIM + t], acc[jj]);
    }
    float sum = (((acc[0] + acc[1]) + (acc[2] + acc[3])) +
                 ((acc[4] + acc[5]) + (acc[6] + acc[7]))) + bm1[t];
    float hid = fmaxf(sum, 0.f);
    float p = hid * Wm2[t];
    for (int off = 32; off; off >>= 1) p += __shfl_down(p, off);
    if ((t & 63) == 0) red[t >> 6] = p;
    __syncthreads();
    if (t == 0) out[b] = red[0] + red[1] + red[2] + red[3] + bm2[0];
}

// ---------------------------------------------------------------------------
extern "C" void kernel_launch(void* const* d_in, const int* in_sizes, int n_in,
                              void* d_out, int out_size, void* d_ws, size_t ws_size,
                              hipStream_t stream) {
    const float* x    = (const float*)d_in[0];
    const int*   ei   = (const int*)d_in[1];
    const int*   batc = (const int*)d_in[2];
    const int*   uidx = (const int*)d_in[3];
    const int*   vidx = (const int*)d_in[4];
    const float* W0   = (const float*)d_in[5];
    const float* b0   = (const float*)d_in[6];
    const float* W1   = (const float*)d_in[7];
    const float* b1   = (const float*)d_in[8];
    const float* W2   = (const float*)d_in[9];
    const float* b2   = (const float*)d_in[10];
    const float* Wm1  = (const float*)d_in[11];
    const float* bm1  = (const float*)d_in[12];
    const float* Wm2  = (const float*)d_in[13];
    const float* bm2  = (const float*)d_in[14];
    float* out = (float*)d_out;

    const int N = in_sizes[0] / DRNL;
    const int E = in_sizes[1] / 2;
    const int B = in_sizes[3];
    const int* src = ei;
    const int* dst = ei + E;

    int SH = 7;
    while (((N + (1 << SH) - 1) >> SH) > 512) ++SH;
    const int NBUCK = (N + (1 << SH) - 1) >> SH;
    const int P = (E + CHUNK - 1) / CHUNK;

    char* w = (char*)d_ws;
    size_t off = 0;
    auto carve = [&](size_t bytes) {
        void* p = w + off;
        off = (off + bytes + 255) & ~(size_t)255;
        return p;
    };
    int*       rowptr = (int*)carve((size_t)(N + 1) * 4);
    int*       colA   = (int*)carve((size_t)E * 4);
    float*     dis    = (float*)carve((size_t)N * 4);
    int*       gstart = (int*)carve((size_t)(B + 1) * 4);
    _Float16*  A16    = (_Float16*)carve((size_t)N * HDIM * 2);
    _Float16*  h16    = (_Float16*)carve((size_t)N * HDIM * 2);
    _Float16*  x16    = (_Float16*)carve((size_t)N * DRNL * 2);
    _Float16*  W0t    = (_Float16*)carve((size_t)DRNL * HDIM * 2);
    _Float16*  W1t    = (_Float16*)carve((size_t)HDIM * HDIM * 2);
    _Float16*  W2t    = (_Float16*)carve((size_t)HDIM * HDIM * 2);
    int*       ghist  = (int*)carve((size_t)NBUCK * P * 4);
    int*       btot   = (int*)carve(512 * 4);
    int*       bbase  = (int*)carve(513 * 4);
    int*       tmpE   = (int*)carve((size_t)E * 4);
    (void)ws_size;

    // prep + histogram in one launch (hist blocks [0,P), misc blocks [P,..))
    k_misc<<<P + 1024, 256, 0, stream>>>(batc, x, W0, W1, W2, gstart,
                                         x16, W0t, W1t, W2t,
                                         dst, ghist, E, P, SH, NBUCK, N, B);
    // atomic-free CSR build (also emits rowptr, dis, and prescales x16)
    k_gbase<<<NBUCK, 256, 0, stream>>>(ghist, btot, P);
    k_btscan<<<1, 256, 0, stream>>>(btot, bbase, rowptr, NBUCK, N, E);
    k_scatter<<<P, 256, 0, stream>>>(src, dst, ghist, bbase, tmpE, E, P, SH, NBUCK);
    k_bsort<<<NBUCK, 256, 0, stream>>>(tmpE, bbase, colA, rowptr, dis, x16, SH, N);

    int gemmb = (N + 63) / 64;     // one 64-row block per 4-wave k_wgemm block
    int NB = (N + 31) / 32;        // agg node-WGs (32 nodes each)
    int NH = (NB + 1) / 2;         // node-WGs per XCD-pair half
    int aggb4 = 8 * NH;            // FBLK=4 grid (multiple of 8)

    // layer 0: agg(x') -> GEMM (relu, scale) -> h' blocked-64
    k_agg<1><<<NB, 256, 0, stream>>>(x16, dis, rowptr, colA, A16, N);
    k_wgemm<DRNL, 1, 1><<<gemmb, 256, 0, stream>>>(A16, W0t, b0, dis, h16, N);
    // layer 1: agg(h') -> GEMM (relu, scale) -> h'
    k_agg<4><<<aggb4, 256, 0, stream>>>(h16, dis, rowptr, colA, A16, N);
    k_wgemm<HDIM, 1, 1><<<gemmb, 256, 0, stream>>>(A16, W1t, b1, dis, h16, N);
    // layer 2: agg(h') -> GEMM (no relu, RAW output for head)
    k_agg<4><<<aggb4, 256, 0, stream>>>(h16, dis, rowptr, colA, A16, N);
    k_wgemm<HDIM, 0, 0><<<gemmb, 256, 0, stream>>>(A16, W2t, b2, dis, h16, N);

    // fused mean-pool + MLP head
    k_head<<<B, 256, 0, stream>>>(h16, gstart, uidx, vidx, Wm1, bm1, Wm2, bm2, out, N);
}

// Round 9
// 285.943 us; speedup vs baseline: 1.1280x; 1.0662x over previous
//
#include <hip/hip_runtime.h>
#include <hip/hip_bf16.h>
#include <stdint.h>

#ifndef DRNL
#define DRNL 64
#define HDIM 256
#endif

#define CHUNK 4096      // edges per hist/scatter block
#define BCAP 3072       // LDS edge capacity per bucket (avg 2046, 22 sigma)
#define SCAP 1536       // LDS col capacity per agg block (avg 512, ~45 sigma)

typedef __attribute__((ext_vector_type(4))) float f32x4;      // MFMA C/D
typedef __attribute__((ext_vector_type(8))) _Float16 f16x8;   // 16B fp16 / MFMA A,B

// ---------------------------------------------------------------------------
// helpers
// ---------------------------------------------------------------------------
__device__ __forceinline__ void async16(void* lds, const void* g) {
    __builtin_amdgcn_global_load_lds(
        (const __attribute__((address_space(1))) void*)g,
        (__attribute__((address_space(3))) void*)(char*)lds, 16, 0, 0);
}

__device__ __forceinline__ int imin(int a, int b) { return a < b ? a : b; }

// ---------------------------------------------------------------------------
// k_misc (+merged hist): blocks [0,P) do the CSR edge histogram; blocks
// [P,..) do order-independent prep: W -> FRAGMENT-ORDER fp16, x16 convert
// (vectorized float4->f16x8), graph bounds.
// Fragment order: Wf[(((cg*KT + kt)*4 + ct)*64 + lane)*8 + j] =
//   W[k = kt*32 + (lane>>4)*8 + j][col = cg*64 + ct*16 + (lane&15)]
// ---------------------------------------------------------------------------
__global__ __launch_bounds__(256) void k_misc(
    const int* __restrict__ batch,
    const float* __restrict__ x,
    const float* __restrict__ W0, const float* __restrict__ W1,
    const float* __restrict__ W2,
    int* __restrict__ gstart,
    _Float16* __restrict__ x16,
    _Float16* __restrict__ W0t, _Float16* __restrict__ W1t,
    _Float16* __restrict__ W2t,
    const int* __restrict__ dst, int* __restrict__ ghist,
    int E, int P, int SH, int NBUCK,
    int N, int B) {
    const int tid = threadIdx.x;

    // ---- merged histogram part ----
    if (blockIdx.x < P) {
        __shared__ int h[512];
        int p = blockIdx.x;
        for (int i = tid; i < NBUCK; i += 256) h[i] = 0;
        __syncthreads();
        int e0 = p * CHUNK, e1 = imin(e0 + CHUNK, E);
        for (int e = e0 + tid; e < e1; e += 256)
            atomicAdd(&h[dst[e] >> SH], 1);          // LDS atomic
        __syncthreads();
        for (int b = tid; b < NBUCK; b += 256)
            ghist[(size_t)b * P + p] = h[b];
        return;
    }

    const int bid  = blockIdx.x - P;
    const int gsz  = (gridDim.x - P) * 256;
    const int gid0 = bid * 256 + tid;

    for (int i = gid0; i < (DRNL + 2 * HDIM) * 256; i += gsz) {
        int b = i >> 8, c = i & 255;
        const float* W; _Float16* T; int k, K;
        if (b < DRNL)            { W = W0; T = W0t; k = b;              K = DRNL; }
        else if (b < DRNL + 256) { W = W1; T = W1t; k = b - DRNL;       K = HDIM; }
        else                     { W = W2; T = W2t; k = b - DRNL - 256; K = HDIM; }
        int KT = K >> 5;
        int cg = c >> 6, ct = (c >> 4) & 3, cl = c & 15;
        int kt = k >> 5, qq = (k >> 3) & 3, j = k & 7;
        int lane = (qq << 4) | cl;
        T[(((size_t)(cg * KT + kt) * 4 + ct) * 64 + lane) * 8 + j] =
            (_Float16)W[(size_t)k * 256 + c];
    }

    // vectorized x -> fp16 (8 elems per thread-step)
    {
        const float4* x4 = (const float4*)x;
        f16x8* xv = (f16x8*)x16;
        int tot = N * DRNL / 8;
        for (int i = gid0; i < tot; i += gsz) {
            float4 a = x4[2 * i], b2 = x4[2 * i + 1];
            f16x8 o;
            o[0] = (_Float16)a.x;  o[1] = (_Float16)a.y;
            o[2] = (_Float16)a.z;  o[3] = (_Float16)a.w;
            o[4] = (_Float16)b2.x; o[5] = (_Float16)b2.y;
            o[6] = (_Float16)b2.z; o[7] = (_Float16)b2.w;
            xv[i] = o;
        }
    }

    for (int i = gid0; i <= N; i += gsz) {
        if (i == 0) {
            int b0 = batch[0];
            for (int b = 0; b <= b0; ++b) gstart[b] = 0;
        } else if (i == N) {
            int bl = batch[N - 1];
            for (int b = bl + 1; b <= B; ++b) gstart[b] = N;
        } else {
            int bp = batch[i - 1], bc = batch[i];
            if (bc != bp)
                for (int b = bp + 1; b <= bc; ++b) gstart[b] = i;
        }
    }
}

// ---------------------------------------------------------------------------
// CSR build, atomic-free. Bucket = dst >> SH (128 nodes/bucket).
// ---------------------------------------------------------------------------
__global__ __launch_bounds__(256) void k_gbase(int* __restrict__ ghist,
                                               int* __restrict__ btot, int P) {
    __shared__ int s[256];
    int b = blockIdx.x, tid = threadIdx.x;
    int* row = ghist + (size_t)b * P;
    int carry = 0;
    for (int base = 0; base < P; base += 256) {
        int idx = base + tid;
        int v = (idx < P) ? row[idx] : 0;
        s[tid] = v;
        __syncthreads();
        for (int o = 1; o < 256; o <<= 1) {
            int t = (tid >= o) ? s[tid - o] : 0;
            __syncthreads();
            s[tid] += t;
            __syncthreads();
        }
        if (idx < P) row[idx] = carry + s[tid] - v;
        carry += s[255];
        __syncthreads();
    }
    if (tid == 0) btot[b] = carry;
}

__global__ __launch_bounds__(256) void k_btscan(const int* __restrict__ btot,
                                                int* __restrict__ bbase,
                                                int* __restrict__ rowptr,
                                                int NBUCK, int N, int E) {
    __shared__ int s[256];
    int tid = threadIdx.x;
    int carry = 0;
    for (int base = 0; base < NBUCK; base += 256) {
        int idx = base + tid;
        int v = (idx < NBUCK) ? btot[idx] : 0;
        s[tid] = v;
        __syncthreads();
        for (int o = 1; o < 256; o <<= 1) {
            int t = (tid >= o) ? s[tid - o] : 0;
            __syncthreads();
            s[tid] += t;
            __syncthreads();
        }
        if (idx < NBUCK) bbase[idx] = carry + s[tid] - v;
        carry += s[255];
        __syncthreads();
    }
    if (tid == 0) { bbase[NBUCK] = E; rowptr[N] = E; }
}

__global__ __launch_bounds__(256) void k_scatter(const int* __restrict__ src,
                                                 const int* __restrict__ dst,
                                                 const int* __restrict__ ghist,
                                                 const int* __restrict__ bbase,
                                                 int* __restrict__ tmp,
                                                 int E, int P, int SH, int NBUCK) {
    __shared__ int base[512];
    int p = blockIdx.x, tid = threadIdx.x;
    for (int b = tid; b < NBUCK; b += 256)
        base[b] = bbase[b] + ghist[(size_t)b * P + p];
    __syncthreads();
    int e0 = p * CHUNK, e1 = imin(e0 + CHUNK, E);
    int msk = (1 << SH) - 1;
    for (int e = e0 + tid; e < e1; e += 256) {
        int d = dst[e];
        int r = atomicAdd(&base[d >> SH], 1);    // LDS atomic = cursor
        tmp[r] = (src[e] << SH) | (d & msk);
    }
}

__global__ __launch_bounds__(256) void k_bsort(const int* __restrict__ tmp,
                                               const int* __restrict__ bbase,
                                               int* __restrict__ col,
                                               int* __restrict__ rowptr,
                                               float* __restrict__ dis,
                                               _Float16* __restrict__ x16,
                                               int SH, int N) {
    __shared__ int cnt[512];
    __shared__ int off[512];
    __shared__ int sscan[256];
    __shared__ int eL[BCAP];
    __shared__ unsigned short rnk[BCAP];
    __shared__ int sL[BCAP];
    int b = blockIdx.x, tid = threadIdx.x;
    int nodes = 1 << SH, node0 = b << SH, msk = nodes - 1;
    int lo = bbase[b], hi = bbase[b + 1], m = hi - lo;
    bool fast = (m <= BCAP);

    for (int i = tid; i < nodes; i += 256) cnt[i] = 0;
    __syncthreads();
    if (fast) {
        for (int i = tid; i < m; i += 256) {
            int v = tmp[lo + i];
            eL[i] = v;
            rnk[i] = (unsigned short)atomicAdd(&cnt[v & msk], 1);
        }
    } else {
        for (int i = tid; i < m; i += 256)
            atomicAdd(&cnt[tmp[lo + i] & msk], 1);
    }
    __syncthreads();
    int carry = 0;
    for (int base = 0; base < nodes; base += 256) {
        int idx = base + tid;
        int v = (idx < nodes) ? cnt[idx] : 0;
        sscan[tid] = v;
        __syncthreads();
        for (int o = 1; o < 256; o <<= 1) {
            int t = (tid >= o) ? sscan[tid - o] : 0;
            __syncthreads();
            sscan[tid] += t;
            __syncthreads();
        }
        if (idx < nodes) off[idx] = carry + sscan[tid] - v;
        carry += sscan[255];
        __syncthreads();
    }
    for (int i = tid; i < nodes; i += 256) {
        int node = node0 + i;
        if (node < N) {
            rowptr[node] = lo + off[i];
            dis[node]    = rsqrtf((float)cnt[i] + 1.f);
        }
    }
    int rlim = imin(nodes, N - node0);
    for (int u = tid; u < rlim * 8; u += 256) {
        int r = u >> 3, c = u & 7;
        float d = rsqrtf((float)cnt[r] + 1.f);
        f16x8* xv = (f16x8*)(x16 + (size_t)(node0 + r) * 64);
        f16x8 v = xv[c];
        f16x8 o;
#pragma unroll
        for (int k = 0; k < 8; ++k) o[k] = (_Float16)((float)v[k] * d);
        xv[c] = o;
    }
    __syncthreads();   // cnt must stay intact until here
    if (fast) {
        for (int i = tid; i < m; i += 256) {
            int v = eL[i];
            sL[off[v & msk] + rnk[i]] = v >> SH;
        }
        __syncthreads();
        for (int i = tid; i < m; i += 256) col[lo + i] = sL[i];
    } else {
        for (int i = tid; i < nodes; i += 256) cnt[i] = 0;
        __syncthreads();
        for (int i = tid; i < m; i += 256) {
            int v = tmp[lo + i];
            int d = v & msk;
            int r = atomicAdd(&cnt[d], 1);
            col[lo + off[d] + r] = v >> SH;
        }
    }
}

// ---------------------------------------------------------------------------
// Aggregation over PRE-SCALED rows h' = h*dis, blocked-64 layout [FBLK][N][64].
// agg[dst] = dis[dst] * (sum_{src} h'[src] + h'[dst])  == exact GCN agg.
// STATIC octet-per-node, unroll-4 (r6-proven; r8's unroll-8 regressed via
// VGPR 52 + masked-slack gathers). NEW: block-level LDS staging of the
// block's contiguous CSR col range — removes the col-load half of the
// per-iteration chained latency (col ~200cy L2 -> ~30cy LDS). The gather
// is the only remaining latency per trip. Bitwise-identical accumulation.
// FBLK=4: feature block f pinned to XCD pair {2f,2f+1} via blockIdx%8.
// ---------------------------------------------------------------------------
template <int FBLK>
__global__ __launch_bounds__(256) void k_agg(const _Float16* __restrict__ hs,
                                             const float* __restrict__ dis,
                                             const int* __restrict__ rowptr,
                                             const int* __restrict__ col,
                                             _Float16* __restrict__ A16, int N) {
    __shared__ int scol[SCAP];
    int node_wg, f;
    if constexpr (FBLK == 4) {
        int wg = blockIdx.x;
        int xcd = wg & 7;
        f = xcd >> 1;
        int half = xcd & 1;
        int NH = gridDim.x >> 3;
        node_wg = half * NH + (wg >> 3);
    } else {
        node_wg = blockIdx.x;
        f = 0;
    }
    // cooperative stage of this block's contiguous col range
    const int n0 = imin(node_wg * 32, N);
    const int n1 = imin(node_wg * 32 + 32, N);
    const int e_lo = rowptr[n0];
    const int cnt = rowptr[n1] - e_lo;
    const bool useLds = (cnt <= SCAP);
    if (useLds)
        for (int i = threadIdx.x; i < cnt; i += 256) scol[i] = col[e_lo + i];
    __syncthreads();

    int lane = threadIdx.x & 63;
    int wv = threadIdx.x >> 6;
    int oct = lane >> 3;
    int fl = lane & 7;
    int gw = node_wg * 32 + wv * 8 + oct;
    bool valid = gw < N;
    int gwc = valid ? gw : N - 1;
    const size_t boff = (size_t)f * ((size_t)N * 64);
    const f16x8* hv = (const f16x8*)(hs + boff);
    float acc[8];
#pragma unroll
    for (int k = 0; k < 8; ++k) acc[k] = 0.f;

    int e0 = rowptr[gwc];
    int e1 = valid ? rowptr[gwc + 1] : e0;

    if (useLds) {
        int j  = e0 - e_lo;
        int eN = valid ? e1 - e_lo : j;
        while (__any(j < eN)) {
            bool a0 = j < eN, a1 = j + 1 < eN, a2 = j + 2 < eN, a3 = j + 3 < eN;
            int s0 = scol[a0 ? j : 0];
            int s1 = scol[a1 ? j + 1 : 0];
            int s2 = scol[a2 ? j + 2 : 0];
            int s3 = scol[a3 ? j + 3 : 0];
            float m0 = a0 ? 1.f : 0.f, m1 = a1 ? 1.f : 0.f;
            float m2 = a2 ? 1.f : 0.f, m3 = a3 ? 1.f : 0.f;
            f16x8 v0 = hv[(size_t)s0 * 8 + fl];
            f16x8 v1 = hv[(size_t)s1 * 8 + fl];
            f16x8 v2 = hv[(size_t)s2 * 8 + fl];
            f16x8 v3 = hv[(size_t)s3 * 8 + fl];
#pragma unroll
            for (int k = 0; k < 8; ++k) acc[k] += m0 * (float)v0[k];
#pragma unroll
            for (int k = 0; k < 8; ++k) acc[k] += m1 * (float)v1[k];
#pragma unroll
            for (int k = 0; k < 8; ++k) acc[k] += m2 * (float)v2[k];
#pragma unroll
            for (int k = 0; k < 8; ++k) acc[k] += m3 * (float)v3[k];
            j += 4;
        }
    } else {
        int j = e0;
        while (__any(j < e1)) {
            bool a0 = j < e1, a1 = j + 1 < e1, a2 = j + 2 < e1, a3 = j + 3 < e1;
            int s0 = col[a0 ? j : 0];
            int s1 = col[a1 ? j + 1 : 0];
            int s2 = col[a2 ? j + 2 : 0];
            int s3 = col[a3 ? j + 3 : 0];
            float m0 = a0 ? 1.f : 0.f, m1 = a1 ? 1.f : 0.f;
            float m2 = a2 ? 1.f : 0.f, m3 = a3 ? 1.f : 0.f;
            f16x8 v0 = hv[(size_t)s0 * 8 + fl];
            f16x8 v1 = hv[(size_t)s1 * 8 + fl];
            f16x8 v2 = hv[(size_t)s2 * 8 + fl];
            f16x8 v3 = hv[(size_t)s3 * 8 + fl];
#pragma unroll
            for (int k = 0; k < 8; ++k) acc[k] += m0 * (float)v0[k];
#pragma unroll
            for (int k = 0; k < 8; ++k) acc[k] += m1 * (float)v1[k];
#pragma unroll
            for (int k = 0; k < 8; ++k) acc[k] += m2 * (float)v2[k];
#pragma unroll
            for (int k = 0; k < 8; ++k) acc[k] += m3 * (float)v3[k];
            j += 4;
        }
    }

    float dn = dis[gwc];
    f16x8 hsv = hv[(size_t)gwc * 8 + fl];
    f16x8 o;
#pragma unroll
    for (int k = 0; k < 8; ++k)
        o[k] = (_Float16)((acc[k] + (float)hsv[k]) * dn);
    if (valid)
        __builtin_nontemporal_store(
            o, (f16x8*)(A16 + boff + (size_t)gw * 64 + fl * 8));
}

// ---------------------------------------------------------------------------
// Barrier-free, fully-coalesced register-W GEMM (r6-proven): out = A@W + bias
// (+relu, +dis scale). A blocked [(K/64)][n][64] fp16; Wf fragment-ordered;
// out blocked [4][n][64].
//  - wave wv owns 64-col group, 64 rows as 4 strips of 16; NO __syncthreads.
//  - W panel: 32 coalesced f16x8 loads (fragment-order), held in VGPRs.
//  - A strip: per-WAVE global_load_lds (coalesced, linear LDS dest,
//    inverse-XOR-swizzled global source) -> wave-local vmcnt(0) ->
//    conflict-free swizzled ds_read_b128 frags.
//  - bias/dis: one coalesced load + __shfl.
//  - epilogue: XOR-swizzled per-wave LDS transpose -> full-line f16x8 stores.
// ---------------------------------------------------------------------------
template <int K, int OUT_RELU, int SCALE>
__global__ __launch_bounds__(256, 1) void k_wgemm(const _Float16* __restrict__ A,
                                                  const _Float16* __restrict__ Wf,
                                                  const float* __restrict__ bias,
                                                  const float* __restrict__ dis,
                                                  _Float16* __restrict__ outh, int n) {
    constexpr int KT  = K / 32;             // k-tiles: 8 (K=256) or 2 (K=64)
    constexpr int NFB = K / 64;             // feature blocks in A
    constexpr int NI  = NFB * 2;            // async16 instrs per strip
    constexpr int STG = NFB * 1024;         // stage halfwords per wave (2KB/fb)
    __shared__ _Float16 sAll[4 * (STG + 1024)];   // per wave: stage + 2KB sO

    const int tid  = threadIdx.x;
    const int lane = tid & 63;
    const int wv   = tid >> 6;              // wave = 64-col group
    const int c15  = lane & 15;
    const int q    = lane >> 4;
    const int row0 = blockIdx.x * 64;
    const size_t bstride = (size_t)n * 64;
    _Float16* sbuf = sAll + wv * (STG + 1024);
    _Float16* sO   = sbuf + STG;
    _Float16* ob   = outh + (size_t)wv * bstride;   // out feature block = wv

    // ---- W panel: 32 (or 8) fully-coalesced 16B loads, fragment order ----
    f16x8 wf[4][KT];
    const _Float16* wp = Wf + ((size_t)wv * KT * 4 * 64 + lane) * 8;
#pragma unroll
    for (int kt = 0; kt < KT; ++kt)
#pragma unroll
        for (int ct = 0; ct < 4; ++ct)
            wf[ct][kt] = *(const f16x8*)(wp + (size_t)((kt * 4 + ct) * 64) * 8);

    // ---- bias / dis via coalesced load + shfl ----
    float bvl = bias[(wv << 6) + lane];
    float bv[4];
#pragma unroll
    for (int ct = 0; ct < 4; ++ct) bv[ct] = __shfl(bvl, (ct << 4) + c15);

    float dsv[4][4];
    if (SCALE) {
        float dvl = dis[imin(row0 + lane, n - 1)];
#pragma unroll
        for (int st = 0; st < 4; ++st)
#pragma unroll
            for (int r = 0; r < 4; ++r)
                dsv[st][r] = __shfl(dvl, (st << 4) + (q << 2) + r);
    }

#pragma unroll
    for (int st = 0; st < 4; ++st) {
        const int r0 = row0 + (st << 4);
        // ---- stage strip (16 rows x K feats) into per-wave LDS ----
        // linear LDS dest; global source pre-swizzled so that swizzled
        // ds_read below sees chunk ch of row at cs = ch ^ (row&7).
#pragma unroll
        for (int i = 0; i < NI; ++i) {
            int s   = (i << 6) + lane;      // 16B slot
            int fb  = s >> 7;
            int row = (s >> 3) & 15;
            int ch  = (s & 7) ^ (row & 7);
            int gr  = imin(r0 + row, n - 1);
            async16(sbuf + (size_t)s * 8,
                    A + (size_t)fb * bstride + (size_t)gr * 64 + ch * 8);
        }
        asm volatile("s_waitcnt vmcnt(0)" ::: "memory");   // wave-local wait
        __builtin_amdgcn_sched_barrier(0);

        // ---- frags: conflict-free swizzled ds_read_b128 ----
        f16x8 af[KT];
#pragma unroll
        for (int kt = 0; kt < KT; ++kt) {
            int off = (kt >> 1) * 1024 + c15 * 64 +
                      ((((kt & 1) * 4 + q) ^ (c15 & 7)) * 8);
            af[kt] = *(const f16x8*)(sbuf + off);
        }

        f32x4 acc[4];
#pragma unroll
        for (int ct = 0; ct < 4; ++ct) acc[ct] = (f32x4)0.f;
#pragma unroll
        for (int kt = 0; kt < KT; ++kt)
#pragma unroll
            for (int ct = 0; ct < 4; ++ct)
                acc[ct] = __builtin_amdgcn_mfma_f32_16x16x32_f16(
                    af[kt], wf[ct][kt], acc[ct], 0, 0, 0);

        // ---- epilogue: swizzled per-wave LDS transpose -> coalesced store
#pragma unroll
        for (int ct = 0; ct < 4; ++ct) {
#pragma unroll
            for (int r = 0; r < 4; ++r) {
                float v = acc[ct][r] + bv[ct];
                if (OUT_RELU) v = fmaxf(v, 0.f);
                if (SCALE) v *= dsv[st][r];
                int row = (q << 2) + r;
                int colx = (ct << 4) + c15;
                int sw = (((colx >> 3) ^ (row & 7)) << 3) | (colx & 7);
                sO[row * 64 + sw] = (_Float16)v;
            }
        }
#pragma unroll
        for (int ps = 0; ps < 2; ++ps) {
            int u = (ps << 6) + lane;       // 0..127
            int rr = u >> 3, ch2 = u & 7;
            f16x8 vv = *(const f16x8*)(sO + rr * 64 + ((ch2 ^ (rr & 7)) << 3));
            if (r0 + rr < n)
                *(f16x8*)(ob + (size_t)(r0 + rr) * 64 + ch2 * 8) = vv;
        }
    }
}

// ---------------------------------------------------------------------------
// fused head: mean-pool + concat + MLP -> out[b]. one block per graph.
// h blocked [4][N][64].
// ---------------------------------------------------------------------------
__global__ __launch_bounds__(256) void k_head(const _Float16* __restrict__ h,
                                              const int* __restrict__ gstart,
                                              const int* __restrict__ u,
                                              const int* __restrict__ v,
                                              const float* __restrict__ Wm1,
                                              const float* __restrict__ bm1,
                                              const float* __restrict__ Wm2,
                                              const float* __restrict__ bm2,
                                              float* __restrict__ out, int N) {
    int b = blockIdx.x;
    int t = threadIdx.x;
    __shared__ float z[3 * HDIM];
    __shared__ float red[4];
    const _Float16* hb = h + (size_t)(t >> 6) * ((size_t)N * 64) + (t & 63);
    int s = gstart[b], e = gstart[b + 1];
    float pa = 0.f;
    int i = s;
    for (; i + 3 < e; i += 4) {
        float a0 = (float)hb[(size_t)i * 64];
        float a1 = (float)hb[(size_t)(i + 1) * 64];
        float a2 = (float)hb[(size_t)(i + 2) * 64];
        float a3 = (float)hb[(size_t)(i + 3) * 64];
        pa += (a0 + a1) + (a2 + a3);
    }
    for (; i < e; ++i) pa += (float)hb[(size_t)i * 64];
    z[t]            = pa / fmaxf((float)(e - s), 1.f);
    z[HDIM + t]     = (float)hb[(size_t)u[b] * 64];
    z[2 * HDIM + t] = (float)hb[(size_t)v[b] * 64];
    __syncthreads();
    float acc[8];
#pragma unroll
    for (int k = 0; k < 8; ++k) acc[k] = 0.f;
    for (int k = 0; k < 3 * HDIM; k += 8) {
#pragma unroll
        for (int jj = 0; jj < 8; ++jj)
            acc[jj] = fmaf(z[k + jj], Wm1[(size_t)(k + jj) * HDIM + t], acc[jj]);
    }
    float sum = (((acc[0] + acc[1]) + (acc[2] + acc[3])) +
                 ((acc[4] + acc[5]) + (acc[6] + acc[7]))) + bm1[t];
    float hid = fmaxf(sum, 0.f);
    float p = hid * Wm2[t];
    for (int off = 32; off; off >>= 1) p += __shfl_down(p, off);
    if ((t & 63) == 0) red[t >> 6] = p;
    __syncthreads();
    if (t == 0) out[b] = red[0] + red[1] + red[2] + red[3] + bm2[0];
}

// ---------------------------------------------------------------------------
extern "C" void kernel_launch(void* const* d_in, const int* in_sizes, int n_in,
                              void* d_out, int out_size, void* d_ws, size_t ws_size,
                              hipStream_t stream) {
    const float* x    = (const float*)d_in[0];
    const int*   ei   = (const int*)d_in[1];
    const int*   batc = (const int*)d_in[2];
    const int*   uidx = (const int*)d_in[3];
    const int*   vidx = (const int*)d_in[4];
    const float* W0   = (const float*)d_in[5];
    const float* b0   = (const float*)d_in[6];
    const float* W1   = (const float*)d_in[7];
    const float* b1   = (const float*)d_in[8];
    const float* W2   = (const float*)d_in[9];
    const float* b2   = (const float*)d_in[10];
    const float* Wm1  = (const float*)d_in[11];
    const float* bm1  = (const float*)d_in[12];
    const float* Wm2  = (const float*)d_in[13];
    const float* bm2  = (const float*)d_in[14];
    float* out = (float*)d_out;

    const int N = in_sizes[0] / DRNL;
    const int E = in_sizes[1] / 2;
    const int B = in_sizes[3];
    const int* src = ei;
    const int* dst = ei + E;

    int SH = 7;
    while (((N + (1 << SH) - 1) >> SH) > 512) ++SH;
    const int NBUCK = (N + (1 << SH) - 1) >> SH;
    const int P = (E + CHUNK - 1) / CHUNK;

    char* w = (char*)d_ws;
    size_t off = 0;
    auto carve = [&](size_t bytes) {
        void* p = w + off;
        off = (off + bytes + 255) & ~(size_t)255;
        return p;
    };
    int*       rowptr = (int*)carve((size_t)(N + 1) * 4);
    int*       colA   = (int*)carve((size_t)E * 4);
    float*     dis    = (float*)carve((size_t)N * 4);
    int*       gstart = (int*)carve((size_t)(B + 1) * 4);
    _Float16*  A16    = (_Float16*)carve((size_t)N * HDIM * 2);
    _Float16*  h16    = (_Float16*)carve((size_t)N * HDIM * 2);
    _Float16*  x16    = (_Float16*)carve((size_t)N * DRNL * 2);
    _Float16*  W0t    = (_Float16*)carve((size_t)DRNL * HDIM * 2);
    _Float16*  W1t    = (_Float16*)carve((size_t)HDIM * HDIM * 2);
    _Float16*  W2t    = (_Float16*)carve((size_t)HDIM * HDIM * 2);
    int*       ghist  = (int*)carve((size_t)NBUCK * P * 4);
    int*       btot   = (int*)carve(512 * 4);
    int*       bbase  = (int*)carve(513 * 4);
    int*       tmpE   = (int*)carve((size_t)E * 4);
    (void)ws_size;

    // prep + histogram in one launch (hist blocks [0,P), misc blocks [P,..))
    k_misc<<<P + 1024, 256, 0, stream>>>(batc, x, W0, W1, W2, gstart,
                                         x16, W0t, W1t, W2t,
                                         dst, ghist, E, P, SH, NBUCK, N, B);
    // atomic-free CSR build (also emits rowptr, dis, and prescales x16)
    k_gbase<<<NBUCK, 256, 0, stream>>>(ghist, btot, P);
    k_btscan<<<1, 256, 0, stream>>>(btot, bbase, rowptr, NBUCK, N, E);
    k_scatter<<<P, 256, 0, stream>>>(src, dst, ghist, bbase, tmpE, E, P, SH, NBUCK);
    k_bsort<<<NBUCK, 256, 0, stream>>>(tmpE, bbase, colA, rowptr, dis, x16, SH, N);

    int gemmb = (N + 63) / 64;     // one 64-row block per 4-wave k_wgemm block
    int NB = (N + 31) / 32;        // agg node-WGs (32 nodes each)
    int NH = (NB + 1) / 2;         // node-WGs per XCD-pair half
    int aggb4 = 8 * NH;            // FBLK=4 grid (multiple of 8)

    // layer 0: agg(x') -> GEMM (relu, scale) -> h' blocked-64
    k_agg<1><<<NB, 256, 0, stream>>>(x16, dis, rowptr, colA, A16, N);
    k_wgemm<DRNL, 1, 1><<<gemmb, 256, 0, stream>>>(A16, W0t, b0, dis, h16, N);
    // layer 1: agg(h') -> GEMM (relu, scale) -> h'
    k_agg<4><<<aggb4, 256, 0, stream>>>(h16, dis, rowptr, colA, A16, N);
    k_wgemm<HDIM, 1, 1><<<gemmb, 256, 0, stream>>>(A16, W1t, b1, dis, h16, N);
    // layer 2: agg(h') -> GEMM (no relu, RAW output for head)
    k_agg<4><<<aggb4, 256, 0, stream>>>(h16, dis, rowptr, colA, A16, N);
    k_wgemm<HDIM, 0, 0><<<gemmb, 256, 0, stream>>>(A16, W2t, b2, dis, h16, N);

    // fused mean-pool + MLP head
    k_head<<<B, 256, 0, stream>>>(h16, gstart, uidx, vidx, Wm1, bm1, Wm2, bm2, out, N);
}